// Round 10
// baseline (882.181 us; speedup 1.0000x reference)
//
#include <hip/hip_runtime.h>

#define NN 100000
#define NG 64

// ======================= gemmU body: U[:,by*64:+64] = x @ Wsel ==============
// by==0 uses W[0]-W[2]; out stride 192. Fin=128.
__device__ __forceinline__ void gemmU_body(const float* __restrict__ x,
                                           const float* __restrict__ W,
                                           float* __restrict__ U, int N,
                                           int bx, int by) {
    __shared__ float As[16][68];
    __shared__ float Bs[16][64];
    const float* Wk = W + by * (128 * 64);
    const float* W2k = W + 2 * (128 * 64);
    int row0 = bx * 64;
    int tid = threadIdx.x;
    int tr = tid >> 4, tc = tid & 15;
    float acc[4][4] = {};
    for (int k0 = 0; k0 < 128; k0 += 16) {
        {
            int r = row0 + (tid >> 2);
            int cc = (tid & 3) * 4;
            float4 v = make_float4(0.f, 0.f, 0.f, 0.f);
            if (r < N) v = *reinterpret_cast<const float4*>(x + (size_t)r * 128 + k0 + cc);
            As[cc + 0][tid >> 2] = v.x;
            As[cc + 1][tid >> 2] = v.y;
            As[cc + 2][tid >> 2] = v.z;
            As[cc + 3][tid >> 2] = v.w;
        }
        {
            int rr = tid >> 4;
            int cc = (tid & 15) * 4;
            float4 v = *reinterpret_cast<const float4*>(Wk + (k0 + rr) * 64 + cc);
            if (by == 0) {
                float4 w2 = *reinterpret_cast<const float4*>(W2k + (k0 + rr) * 64 + cc);
                v.x -= w2.x; v.y -= w2.y; v.z -= w2.z; v.w -= w2.w;
            }
            *reinterpret_cast<float4*>(&Bs[rr][cc]) = v;
        }
        __syncthreads();
#pragma unroll
        for (int kk = 0; kk < 16; ++kk) {
            float4 a = *reinterpret_cast<const float4*>(&As[kk][tr * 4]);
            float4 b = *reinterpret_cast<const float4*>(&Bs[kk][tc * 4]);
            acc[0][0] += a.x * b.x; acc[0][1] += a.x * b.y; acc[0][2] += a.x * b.z; acc[0][3] += a.x * b.w;
            acc[1][0] += a.y * b.x; acc[1][1] += a.y * b.y; acc[1][2] += a.y * b.z; acc[1][3] += a.y * b.w;
            acc[2][0] += a.z * b.x; acc[2][1] += a.z * b.y; acc[2][2] += a.z * b.z; acc[2][3] += a.z * b.w;
            acc[3][0] += a.w * b.x; acc[3][1] += a.w * b.y; acc[3][2] += a.w * b.z; acc[3][3] += a.w * b.w;
        }
        __syncthreads();
    }
    int cbase = by * 64;
#pragma unroll
    for (int i = 0; i < 4; ++i) {
        int r = row0 + tr * 4 + i;
        if (r >= N) continue;
#pragma unroll
        for (int j = 0; j < 4; ++j)
            U[(size_t)r * 192 + cbase + tc * 4 + j] = acc[i][j];
    }
}

// ====== pre1: gemmU(y=0,1,2) blocks FIRST, then edges (deg+hist+rank) =======
__global__ __launch_bounds__(256) void k_pre1(const float* __restrict__ x,
                                              const float* __restrict__ W1,
                                              float* __restrict__ U, int N,
                                              const int* __restrict__ src,
                                              const int* __restrict__ dst,
                                              const float* __restrict__ ew,
                                              float* __restrict__ deg,
                                              int* __restrict__ cnt,
                                              int* __restrict__ rank, int E,
                                              int gx) {
    int b = blockIdx.x;
    if (b < 3 * gx) {
        gemmU_body(x, W1, U, N, b % gx, b / gx);
    } else {
        int e = (b - 3 * gx) * 256 + threadIdx.x;
        if (e < E) {
            atomicAdd(&deg[src[e]], ew[e]);
            rank[e] = atomicAdd(&cnt[dst[e]], 1);
        }
    }
}

// ====== fill (no atomics): pos = starts[dst] + rank ========================
__global__ __launch_bounds__(256) void k_fill(const int* __restrict__ src,
                                              const int* __restrict__ dst,
                                              const float* __restrict__ ew,
                                              const float* __restrict__ dinv,
                                              const int* __restrict__ starts,
                                              const int* __restrict__ rank,
                                              int2* __restrict__ csr, int E) {
    int e = blockIdx.x * 256 + threadIdx.x;
    if (e >= E) return;
    int s = src[e], d = dst[e];
    int pos = starts[d] + rank[e];
    float w = -dinv[s] * ew[e] * dinv[d];
    csr[pos] = make_int2(s, __float_as_int(w));
}

// ======== scan pass A (+ fused dinv + degree-bin histogram) ================
__global__ __launch_bounds__(1024) void k_scan_a(int* __restrict__ cnt,
                                                 int* __restrict__ bsum,
                                                 float* __restrict__ deg,
                                                 int* __restrict__ dbin, int N) {
    __shared__ int sh[1024];
    __shared__ int hb[64];
    int t = threadIdx.x;
    if (t < 64) hb[t] = 0;
    int idx = blockIdx.x * 1024 + t;
    int v = (idx < N) ? cnt[idx] : 0;
    if (idx < N) {
        float d = deg[idx];
        deg[idx] = (d > 0.f) ? rsqrtf(fmaxf(d, 1e-30f)) : 0.f;
    }
    sh[t] = v;
    __syncthreads();
#pragma unroll
    for (int off = 1; off < 1024; off <<= 1) {
        int tmp = (t >= off) ? sh[t - off] : 0;
        __syncthreads();
        sh[t] += tmp;
        __syncthreads();
    }
    if (idx < N) cnt[idx] = sh[t] - v;  // exclusive
    if (t == 1023) bsum[blockIdx.x] = sh[1023];
    // degree-bin histogram (LDS-aggregated)
    if (idx < N) atomicAdd(&hb[min(v, 63)], 1);
    __syncthreads();
    if (t < 64) {
        int c = hb[t];
        if (c) atomicAdd(&dbin[t], c);
    }
}

// ======== scan pass B (block sums + degree-bin exclusive scan) =============
__global__ __launch_bounds__(128) void k_scan_b(const int* __restrict__ bsum,
                                                int* __restrict__ boff, int nb,
                                                const int* __restrict__ dbin,
                                                int* __restrict__ dcur) {
    __shared__ int sh[128];
    __shared__ int sb[64];
    int t = threadIdx.x;
    int v = (t < nb) ? bsum[t] : 0;
    sh[t] = v;
    int dv = (t < 64) ? dbin[t] : 0;
    if (t < 64) sb[t] = dv;
    __syncthreads();
#pragma unroll
    for (int off = 1; off < 128; off <<= 1) {
        int tmp = (t >= off) ? sh[t - off] : 0;
        int tmp2 = (t >= off && t < 64) ? sb[t - off] : 0;
        __syncthreads();
        sh[t] += tmp;
        if (t < 64) sb[t] += tmp2;
        __syncthreads();
    }
    if (t < nb) boff[t] = sh[t] - v;
    if (t < 64) dcur[t] = sb[t] - dv;  // exclusive bin starts (working cursor)
}

__global__ __launch_bounds__(1024) void k_scan_c(int* __restrict__ cnt,
                                                 const int* __restrict__ boff,
                                                 int N, int E) {
    int idx = blockIdx.x * 1024 + threadIdx.x;
    if (idx < N) cnt[idx] += boff[blockIdx.x];
    if (idx == 0) cnt[N] = E;  // sentinel row end
}

// ======== degree-sorted scatter: perm groups equal-degree nodes ============
__global__ __launch_bounds__(1024) void k_dscat(const int* __restrict__ starts,
                                                int* __restrict__ dcur,
                                                int* __restrict__ perm, int N) {
    __shared__ int lcnt[64];
    __shared__ int lbase[64];
    int t = threadIdx.x;
    int idx = blockIdx.x * 1024 + t;
    if (t < 64) lcnt[t] = 0;
    __syncthreads();
    int bin = 0, lrank = 0;
    bool valid = idx < N;
    if (valid) {
        int d = starts[idx + 1] - starts[idx];
        bin = min(d, 63);
        lrank = atomicAdd(&lcnt[bin], 1);
    }
    __syncthreads();
    if (t < 64) {
        int c = lcnt[t];
        lbase[t] = c ? atomicAdd(&dcur[t], c) : 0;
    }
    __syncthreads();
    if (valid) perm[lbase[bin] + lrank] = idx;
}

// ================= propagation (CSR gather, F=64, packed int2) =============
// Nodes processed in degree-sorted order via perm (uniform trip count/wave).
// MODE 0: out = acc
// MODE 1: out = 2*acc - t0                      (layer-3 T2 step)
// MODE 3: out = t0 + 2*acc                      (R-step, t0 = U1/V1 slice)
// MODE 4: out = relu(t0 + acc + bias)           (H-step, t0 = U0'/V0' slice)
template <int MODE>
__global__ __launch_bounds__(256) void k_prop64(const int* __restrict__ rs,
                                                const int2* __restrict__ csr,
                                                const int* __restrict__ perm,
                                                const float* __restrict__ in,
                                                int istride,
                                                float* __restrict__ out,
                                                const float* __restrict__ t0,
                                                int t0s,
                                                const float* __restrict__ bias,
                                                int N) {
    int tid = blockIdx.x * 256 + threadIdx.x;
    int nid = tid >> 4;
    int lane = tid & 15;
    if (nid >= N) return;
    int node = perm[nid];
    int start = rs[node];
    int end = rs[node + 1];
    float4 acc = make_float4(0.f, 0.f, 0.f, 0.f);
    int c4 = lane * 4;
    int j = start;
    for (; j + 4 <= end; j += 4) {
        int2 e0 = csr[j + 0], e1 = csr[j + 1], e2 = csr[j + 2], e3 = csr[j + 3];
        float w0 = __int_as_float(e0.y), w1 = __int_as_float(e1.y);
        float w2 = __int_as_float(e2.y), w3 = __int_as_float(e3.y);
        float4 v0 = *reinterpret_cast<const float4*>(in + (size_t)e0.x * istride + c4);
        float4 v1 = *reinterpret_cast<const float4*>(in + (size_t)e1.x * istride + c4);
        float4 v2 = *reinterpret_cast<const float4*>(in + (size_t)e2.x * istride + c4);
        float4 v3 = *reinterpret_cast<const float4*>(in + (size_t)e3.x * istride + c4);
        acc.x += w0 * v0.x + w1 * v1.x + w2 * v2.x + w3 * v3.x;
        acc.y += w0 * v0.y + w1 * v1.y + w2 * v2.y + w3 * v3.y;
        acc.z += w0 * v0.z + w1 * v1.z + w2 * v2.z + w3 * v3.z;
        acc.w += w0 * v0.w + w1 * v1.w + w2 * v2.w + w3 * v3.w;
    }
    for (; j < end; ++j) {
        int2 e0 = csr[j];
        float w0 = __int_as_float(e0.y);
        float4 v0 = *reinterpret_cast<const float4*>(in + (size_t)e0.x * istride + c4);
        acc.x += w0 * v0.x;
        acc.y += w0 * v0.y;
        acc.z += w0 * v0.z;
        acc.w += w0 * v0.w;
    }
    float4 r;
    if (MODE == 0) {
        r = acc;
    } else if (MODE == 1) {
        float4 t = *reinterpret_cast<const float4*>(t0 + (size_t)node * t0s + c4);
        r.x = 2.f * acc.x - t.x;
        r.y = 2.f * acc.y - t.y;
        r.z = 2.f * acc.z - t.z;
        r.w = 2.f * acc.w - t.w;
    } else if (MODE == 3) {
        float4 t = *reinterpret_cast<const float4*>(t0 + (size_t)node * t0s + c4);
        r.x = t.x + 2.f * acc.x;
        r.y = t.y + 2.f * acc.y;
        r.z = t.z + 2.f * acc.z;
        r.w = t.w + 2.f * acc.w;
    } else {
        float4 t = *reinterpret_cast<const float4*>(t0 + (size_t)node * t0s + c4);
        float4 bb = *reinterpret_cast<const float4*>(bias + c4);
        r.x = fmaxf(t.x + acc.x + bb.x, 0.f);
        r.y = fmaxf(t.y + acc.y + bb.y, 0.f);
        r.z = fmaxf(t.z + acc.z + bb.z, 0.f);
        r.w = fmaxf(t.w + acc.w + bb.w, 0.f);
    }
    *reinterpret_cast<float4*>(out + (size_t)node * 64 + c4) = r;
}

// ====== gemmD: V = H @ [W0-W2 | W1 | W2]  (Fin=64, out stride 192) =========
__global__ __launch_bounds__(256) void k_gemmD(const float* __restrict__ H,
                                               const float* __restrict__ W,
                                               float* __restrict__ V, int N) {
    __shared__ float As[16][68];
    __shared__ float Bs[16][64];
    int by = blockIdx.y;
    const float* Wk = W + by * (64 * 64);
    const float* W2k = W + 2 * (64 * 64);
    int row0 = blockIdx.x * 64;
    int tid = threadIdx.x;
    int tr = tid >> 4, tc = tid & 15;
    float acc[4][4] = {};
    for (int k0 = 0; k0 < 64; k0 += 16) {
        {
            int r = row0 + (tid >> 2);
            int cc = (tid & 3) * 4;
            float4 v = make_float4(0.f, 0.f, 0.f, 0.f);
            if (r < N) v = *reinterpret_cast<const float4*>(H + (size_t)r * 64 + k0 + cc);
            As[cc + 0][tid >> 2] = v.x;
            As[cc + 1][tid >> 2] = v.y;
            As[cc + 2][tid >> 2] = v.z;
            As[cc + 3][tid >> 2] = v.w;
        }
        {
            int rr = tid >> 4;
            int cc = (tid & 15) * 4;
            float4 v = *reinterpret_cast<const float4*>(Wk + (k0 + rr) * 64 + cc);
            if (by == 0) {
                float4 w2 = *reinterpret_cast<const float4*>(W2k + (k0 + rr) * 64 + cc);
                v.x -= w2.x; v.y -= w2.y; v.z -= w2.z; v.w -= w2.w;
            }
            *reinterpret_cast<float4*>(&Bs[rr][cc]) = v;
        }
        __syncthreads();
#pragma unroll
        for (int kk = 0; kk < 16; ++kk) {
            float4 a = *reinterpret_cast<const float4*>(&As[kk][tr * 4]);
            float4 b = *reinterpret_cast<const float4*>(&Bs[kk][tc * 4]);
            acc[0][0] += a.x * b.x; acc[0][1] += a.x * b.y; acc[0][2] += a.x * b.z; acc[0][3] += a.x * b.w;
            acc[1][0] += a.y * b.x; acc[1][1] += a.y * b.y; acc[1][2] += a.y * b.z; acc[1][3] += a.y * b.w;
            acc[2][0] += a.z * b.x; acc[2][1] += a.z * b.y; acc[2][2] += a.z * b.z; acc[2][3] += a.z * b.w;
            acc[3][0] += a.w * b.x; acc[3][1] += a.w * b.y; acc[3][2] += a.w * b.z; acc[3][3] += a.w * b.w;
        }
        __syncthreads();
    }
    int cbase = by * 64;
#pragma unroll
    for (int i = 0; i < 4; ++i) {
        int r = row0 + tr * 4 + i;
        if (r >= N) continue;
#pragma unroll
        for (int j = 0; j < 4; ++j)
            V[(size_t)r * 192 + cbase + tc * 4 + j] = acc[i][j];
    }
}

// ====== 3-term GEMM + pool (layer 3): relu(T0@W0+T1@W1+T2@W2+b) -> sums =====
__global__ __launch_bounds__(256) void k_gemm3p(const float* __restrict__ T0,
                                                const float* __restrict__ T1,
                                                const float* __restrict__ T2,
                                                const float* __restrict__ W,
                                                const float* __restrict__ bias,
                                                int N, int Fin, int Fout,
                                                const int* __restrict__ batch,
                                                float* __restrict__ sums) {
    __shared__ float As[16][68];
    __shared__ float Bs[16][64];
    int row0 = blockIdx.x * 64;
    int col0 = blockIdx.y * 64;
    int tid = threadIdx.x;
    int tr = tid >> 4, tc = tid & 15;
    float acc[4][4] = {};
    const float* Ts[3] = {T0, T1, T2};
    for (int k = 0; k < 3; ++k) {
        const float* T = Ts[k];
        const float* Wk = W + k * Fin * Fout;
        for (int k0 = 0; k0 < Fin; k0 += 16) {
            {
                int r = row0 + (tid >> 2);
                int cc = (tid & 3) * 4;
                float4 v = make_float4(0.f, 0.f, 0.f, 0.f);
                if (r < N)
                    v = *reinterpret_cast<const float4*>(T + (size_t)r * Fin + k0 + cc);
                As[cc + 0][tid >> 2] = v.x;
                As[cc + 1][tid >> 2] = v.y;
                As[cc + 2][tid >> 2] = v.z;
                As[cc + 3][tid >> 2] = v.w;
            }
            {
                int rr = tid >> 4;
                int cc = (tid & 15) * 4;
                *reinterpret_cast<float4*>(&Bs[rr][cc]) =
                    *reinterpret_cast<const float4*>(Wk + (size_t)(k0 + rr) * Fout + col0 + cc);
            }
            __syncthreads();
#pragma unroll
            for (int kk = 0; kk < 16; ++kk) {
                float4 a = *reinterpret_cast<const float4*>(&As[kk][tr * 4]);
                float4 b = *reinterpret_cast<const float4*>(&Bs[kk][tc * 4]);
                acc[0][0] += a.x * b.x; acc[0][1] += a.x * b.y; acc[0][2] += a.x * b.z; acc[0][3] += a.x * b.w;
                acc[1][0] += a.y * b.x; acc[1][1] += a.y * b.y; acc[1][2] += a.y * b.z; acc[1][3] += a.y * b.w;
                acc[2][0] += a.z * b.x; acc[2][1] += a.z * b.y; acc[2][2] += a.z * b.z; acc[2][3] += a.z * b.w;
                acc[3][0] += a.w * b.x; acc[3][1] += a.w * b.y; acc[3][2] += a.w * b.z; acc[3][3] += a.w * b.w;
            }
            __syncthreads();
        }
    }
    __shared__ float ps[64];
    int b0 = batch[row0];
    int b1v = batch[min(row0 + 63, N - 1)];
    if (b0 == b1v) {
        if (tid < 64) ps[tid] = 0.f;
        __syncthreads();
#pragma unroll
        for (int j = 0; j < 4; ++j) {
            float cs = 0.f;
#pragma unroll
            for (int i = 0; i < 4; ++i) {
                int r = row0 + tr * 4 + i;
                if (r < N) cs += fmaxf(acc[i][j] + bias[col0 + tc * 4 + j], 0.f);
            }
            atomicAdd(&ps[tc * 4 + j], cs);
        }
        __syncthreads();
        if (tid < 64) atomicAdd(&sums[b0 * 128 + col0 + tid], ps[tid]);
    } else {
#pragma unroll
        for (int i = 0; i < 4; ++i) {
            int r = row0 + tr * 4 + i;
            if (r >= N) continue;
#pragma unroll
            for (int j = 0; j < 4; ++j) {
                int cgl = col0 + tc * 4 + j;
                float v = fmaxf(acc[i][j] + bias[cgl], 0.f);
                atomicAdd(&sums[batch[r] * 128 + cgl], v);
            }
        }
    }
}

// ================= head (graph starts computed in-kernel) =================
__global__ __launch_bounds__(640) void k_head(const float* __restrict__ sums,
                                              const int* __restrict__ batch, int N,
                                              const float* __restrict__ linW,
                                              const float* __restrict__ linb,
                                              float* __restrict__ out) {
    __shared__ int st[65];
    int t = threadIdx.x;
    if (t <= 64) {
        if (t == 64) {
            st[64] = N;
        } else {
            int lo = 0, hi = N;
            while (lo < hi) {
                int mid = (lo + hi) >> 1;
                if (batch[mid] < t) lo = mid + 1; else hi = mid;
            }
            st[t] = lo;
        }
    }
    __syncthreads();
    if (t >= NG * 10) return;
    int g = t / 10, o = t % 10;
    float cnt = (float)(st[g + 1] - st[g]);
    float inv = 1.f / fmaxf(cnt, 1.f);
    float acc = 0.f;
#pragma unroll 8
    for (int k = 0; k < 128; ++k) acc += sums[g * 128 + k] * linW[k * 10 + o];
    out[t] = acc * inv + linb[o];
}

// ================= launch =================
extern "C" void kernel_launch(void* const* d_in, const int* in_sizes, int n_in,
                              void* d_out, int out_size, void* d_ws, size_t ws_size,
                              hipStream_t stream) {
    const float* x = (const float*)d_in[0];
    const int* ei = (const int*)d_in[1];
    const float* ew = (const float*)d_in[2];
    const int* batch = (const int*)d_in[3];
    const float* W1 = (const float*)d_in[4];
    const float* b1 = (const float*)d_in[5];
    const float* W2 = (const float*)d_in[6];
    const float* b2 = (const float*)d_in[7];
    const float* W3 = (const float*)d_in[8];
    const float* b3 = (const float*)d_in[9];
    const float* linW = (const float*)d_in[10];
    const float* linb = (const float*)d_in[11];

    const int E = in_sizes[1] / 2;   // 1,600,000
    const int N = in_sizes[0] / 128; // 100,000
    const int* src = ei;
    const int* dst = ei + E;

    float* ws = (float*)d_ws;
    int2*  csr     = (int2*)ws;                        // E entries -> 3,200,512 f
    int*   rank    = (int*)(ws + 3200512);             // 1,600,256
    int*   cursor  = rank + 1600256;                   // N+1 starts; [100224..100287] = dbin (zeroed)
    float* dinv    = (float*)(cursor + 100352);        // 100,352 (deg then dinv)
    int*   bsum    = (int*)(dinv + 100352);            // 256
    int*   boff    = bsum + 256;                       // 128 used; [128..191] = dcur
    float* U       = (float*)(boff + 256);             // 19,200,256 (N x 192; V reuses)
    float* R       = U + 19200256;                     // 6,400,256 (R1/R2, then A3)
    float* H1      = R + 6400256;                      // 6,400,256
    float* H2      = H1 + 6400256;                     // 6,400,256
    float* B3      = H2 + 6400256;                     // 6,400,256
    float* sums    = B3 + 6400256;                     // 8,192
    int*   perm    = (int*)(sums + 8192);              // 100,352

    int* dbin = cursor + 100224;   // inside zeroed cursor region
    int* dcur = boff + 128;        // written by k_scan_b

    float* A3 = R;

    const int TB = 256;
    auto blocks = [](long long t, int b) { return (int)((t + b - 1) / b); };
    const int PG64 = blocks((long long)N * 16, TB);
    const int NB = (N + 1023) / 1024;       // scan blocks
    const int GX = (N + 63) / 64;           // gemm x-blocks
    const int EB = blocks(E, TB);           // edge blocks

    // ---- memsets up front (cursor[N+1]+dbin + deg contiguous; sums) ----
    hipMemsetAsync(cursor, 0, (100352 + 100352) * sizeof(int), stream);
    hipMemsetAsync(sums, 0, NG * 128 * sizeof(float), stream);

    // ---- pre1: gemmU(y0,y1,y2) first, then edges (deg + hist + rank) ----
    k_pre1<<<3 * GX + EB, TB, 0, stream>>>(x, W1, U, N, src, dst, ew,
                                           dinv, cursor, rank, E, GX);
    // ---- dinv + scan (cursor -> row starts; cursor[N]=E) + degree bins ----
    k_scan_a<<<NB, 1024, 0, stream>>>(cursor, bsum, dinv, dbin, N);
    k_scan_b<<<1, 128, 0, stream>>>(bsum, boff, NB, dbin, dcur);
    k_scan_c<<<NB, 1024, 0, stream>>>(cursor, boff, N, E);
    // ---- degree-sorted node permutation + CSR fill (no atomics) ----
    k_dscat<<<NB, 1024, 0, stream>>>(cursor, dcur, perm, N);
    k_fill<<<EB, TB, 0, stream>>>(src, dst, ew, dinv, cursor, rank, csr, E);

    // ---- layer 1: R = U1 + 2*L(U2); H1 = relu(U0' + L(R) + b1) ----
    k_prop64<3><<<PG64, TB, 0, stream>>>(cursor, csr, perm, U + 128, 192, R,
                                         U + 64, 192, nullptr, N);
    k_prop64<4><<<PG64, TB, 0, stream>>>(cursor, csr, perm, R, 64, H1,
                                         U, 192, b1, N);

    // ---- layer 2: V = H1@[W0-W2|W1|W2]; R = V1 + 2*L(V2); H2 = relu(V0'+L(R)+b2)
    {
        dim3 g(GX, 3);
        k_gemmD<<<g, TB, 0, stream>>>(H1, W2, U, N);
    }
    k_prop64<3><<<PG64, TB, 0, stream>>>(cursor, csr, perm, U + 128, 192, R,
                                         U + 64, 192, nullptr, N);
    k_prop64<4><<<PG64, TB, 0, stream>>>(cursor, csr, perm, R, 64, H2,
                                         U, 192, b2, N);

    // ---- layer 3: A3 = L(H2); B3 = 2*L(A3) - H2; gemm3+pool ----
    k_prop64<0><<<PG64, TB, 0, stream>>>(cursor, csr, perm, H2, 64, A3,
                                         nullptr, 0, nullptr, N);
    k_prop64<1><<<PG64, TB, 0, stream>>>(cursor, csr, perm, A3, 64, B3,
                                         H2, 64, nullptr, N);
    {
        dim3 g(GX, 2);
        k_gemm3p<<<g, TB, 0, stream>>>(H2, A3, B3, W3, b3, N, 64, 128, batch, sums);
    }

    // ---- head ----
    k_head<<<1, 640, 0, stream>>>(sums, batch, N, linW, linb, (float*)d_out);
}

// Round 11
// 709.436 us; speedup vs baseline: 1.2435x; 1.2435x over previous
//
#include <hip/hip_runtime.h>

#define NN 100000
#define NG 64

// ---------------- bf16 helpers (storage only; math in fp32) ----------------
__device__ __forceinline__ float bf2f(ushort s) {
    return __uint_as_float(((unsigned int)s) << 16);
}
__device__ __forceinline__ ushort f2bf(float f) {
    unsigned int u = __float_as_uint(f);
    u += 0x7FFFu + ((u >> 16) & 1u);  // round-to-nearest-even
    return (ushort)(u >> 16);
}
__device__ __forceinline__ float4 ldbf4(const ushort* p) {
    ushort4 s = *reinterpret_cast<const ushort4*>(p);
    return make_float4(bf2f(s.x), bf2f(s.y), bf2f(s.z), bf2f(s.w));
}
__device__ __forceinline__ void stbf4(ushort* p, float a, float b, float c, float d) {
    ushort4 s = make_ushort4(f2bf(a), f2bf(b), f2bf(c), f2bf(d));
    *reinterpret_cast<ushort4*>(p) = s;
}

// ======================= gemmU body: U[:,by*64:+64] = x @ Wsel ==============
// by==0 uses W[0]-W[2]; out stride 192 (bf16). Fin=128, x fp32.
__device__ __forceinline__ void gemmU_body(const float* __restrict__ x,
                                           const float* __restrict__ W,
                                           ushort* __restrict__ U, int N,
                                           int bx, int by) {
    __shared__ float As[16][68];
    __shared__ float Bs[16][64];
    const float* Wk = W + by * (128 * 64);
    const float* W2k = W + 2 * (128 * 64);
    int row0 = bx * 64;
    int tid = threadIdx.x;
    int tr = tid >> 4, tc = tid & 15;
    float acc[4][4] = {};
    for (int k0 = 0; k0 < 128; k0 += 16) {
        {
            int r = row0 + (tid >> 2);
            int cc = (tid & 3) * 4;
            float4 v = make_float4(0.f, 0.f, 0.f, 0.f);
            if (r < N) v = *reinterpret_cast<const float4*>(x + (size_t)r * 128 + k0 + cc);
            As[cc + 0][tid >> 2] = v.x;
            As[cc + 1][tid >> 2] = v.y;
            As[cc + 2][tid >> 2] = v.z;
            As[cc + 3][tid >> 2] = v.w;
        }
        {
            int rr = tid >> 4;
            int cc = (tid & 15) * 4;
            float4 v = *reinterpret_cast<const float4*>(Wk + (k0 + rr) * 64 + cc);
            if (by == 0) {
                float4 w2 = *reinterpret_cast<const float4*>(W2k + (k0 + rr) * 64 + cc);
                v.x -= w2.x; v.y -= w2.y; v.z -= w2.z; v.w -= w2.w;
            }
            *reinterpret_cast<float4*>(&Bs[rr][cc]) = v;
        }
        __syncthreads();
#pragma unroll
        for (int kk = 0; kk < 16; ++kk) {
            float4 a = *reinterpret_cast<const float4*>(&As[kk][tr * 4]);
            float4 b = *reinterpret_cast<const float4*>(&Bs[kk][tc * 4]);
            acc[0][0] += a.x * b.x; acc[0][1] += a.x * b.y; acc[0][2] += a.x * b.z; acc[0][3] += a.x * b.w;
            acc[1][0] += a.y * b.x; acc[1][1] += a.y * b.y; acc[1][2] += a.y * b.z; acc[1][3] += a.y * b.w;
            acc[2][0] += a.z * b.x; acc[2][1] += a.z * b.y; acc[2][2] += a.z * b.z; acc[2][3] += a.z * b.w;
            acc[3][0] += a.w * b.x; acc[3][1] += a.w * b.y; acc[3][2] += a.w * b.z; acc[3][3] += a.w * b.w;
        }
        __syncthreads();
    }
    int cbase = by * 64;
#pragma unroll
    for (int i = 0; i < 4; ++i) {
        int r = row0 + tr * 4 + i;
        if (r >= N) continue;
        stbf4(U + (size_t)r * 192 + cbase + tc * 4,
              acc[i][0], acc[i][1], acc[i][2], acc[i][3]);
    }
}

// ====== pre1: gemmU(y=0,1,2) blocks FIRST, then edges (deg+hist+rank) =======
__global__ __launch_bounds__(256) void k_pre1(const float* __restrict__ x,
                                              const float* __restrict__ W1,
                                              ushort* __restrict__ U, int N,
                                              const int* __restrict__ src,
                                              const int* __restrict__ dst,
                                              const float* __restrict__ ew,
                                              float* __restrict__ deg,
                                              int* __restrict__ cnt,
                                              int* __restrict__ rank, int E,
                                              int gx) {
    int b = blockIdx.x;
    if (b < 3 * gx) {
        gemmU_body(x, W1, U, N, b % gx, b / gx);
    } else {
        int e = (b - 3 * gx) * 256 + threadIdx.x;
        if (e < E) {
            atomicAdd(&deg[src[e]], ew[e]);
            rank[e] = atomicAdd(&cnt[dst[e]], 1);
        }
    }
}

// ====== fill (no atomics): pos = starts[dst] + rank ========================
__global__ __launch_bounds__(256) void k_fill(const int* __restrict__ src,
                                              const int* __restrict__ dst,
                                              const float* __restrict__ ew,
                                              const float* __restrict__ dinv,
                                              const int* __restrict__ starts,
                                              const int* __restrict__ rank,
                                              int2* __restrict__ csr, int E) {
    int e = blockIdx.x * 256 + threadIdx.x;
    if (e >= E) return;
    int s = src[e], d = dst[e];
    int pos = starts[d] + rank[e];
    float w = -dinv[s] * ew[e] * dinv[d];
    csr[pos] = make_int2(s, __float_as_int(w));
}

// ================= scan pass A (+ fused dinv) =================
__global__ __launch_bounds__(1024) void k_scan_a(int* __restrict__ cnt,
                                                 int* __restrict__ bsum,
                                                 float* __restrict__ deg, int N) {
    __shared__ int sh[1024];
    int t = threadIdx.x;
    int idx = blockIdx.x * 1024 + t;
    int v = (idx < N) ? cnt[idx] : 0;
    if (idx < N) {
        float d = deg[idx];
        deg[idx] = (d > 0.f) ? rsqrtf(fmaxf(d, 1e-30f)) : 0.f;
    }
    sh[t] = v;
    __syncthreads();
#pragma unroll
    for (int off = 1; off < 1024; off <<= 1) {
        int tmp = (t >= off) ? sh[t - off] : 0;
        __syncthreads();
        sh[t] += tmp;
        __syncthreads();
    }
    if (idx < N) cnt[idx] = sh[t] - v;  // exclusive
    if (t == 1023) bsum[blockIdx.x] = sh[1023];
}

__global__ __launch_bounds__(128) void k_scan_b(const int* __restrict__ bsum,
                                                int* __restrict__ boff, int nb) {
    __shared__ int sh[128];
    int t = threadIdx.x;
    int v = (t < nb) ? bsum[t] : 0;
    sh[t] = v;
    __syncthreads();
#pragma unroll
    for (int off = 1; off < 128; off <<= 1) {
        int tmp = (t >= off) ? sh[t - off] : 0;
        __syncthreads();
        sh[t] += tmp;
        __syncthreads();
    }
    if (t < nb) boff[t] = sh[t] - v;
}

__global__ __launch_bounds__(1024) void k_scan_c(int* __restrict__ cnt,
                                                 const int* __restrict__ boff,
                                                 int N, int E) {
    int idx = blockIdx.x * 1024 + threadIdx.x;
    if (idx < N) cnt[idx] += boff[blockIdx.x];
    if (idx == 0) cnt[N] = E;  // sentinel row end
}

// ========== propagation (CSR gather, F=64 bf16 rows, packed int2) ==========
// MODE 0: out = acc
// MODE 1: out = 2*acc - t0                      (layer-3 T2 step)
// MODE 3: out = t0 + 2*acc                      (R-step, t0 = U1/V1 slice)
// MODE 4: out = relu(t0 + acc + bias)           (H-step, t0 = U0'/V0' slice)
template <int MODE>
__global__ __launch_bounds__(256) void k_prop64(const int* __restrict__ rs,
                                                const int2* __restrict__ csr,
                                                const ushort* __restrict__ in,
                                                int istride,
                                                ushort* __restrict__ out,
                                                const ushort* __restrict__ t0,
                                                int t0s,
                                                const float* __restrict__ bias,
                                                int N) {
    int tid = blockIdx.x * 256 + threadIdx.x;
    int node = tid >> 4;
    int lane = tid & 15;
    if (node >= N) return;
    int start = rs[node];
    int end = rs[node + 1];
    float4 acc = make_float4(0.f, 0.f, 0.f, 0.f);
    int c4 = lane * 4;
    int j = start;
    for (; j + 4 <= end; j += 4) {
        int2 e0 = csr[j + 0], e1 = csr[j + 1], e2 = csr[j + 2], e3 = csr[j + 3];
        float w0 = __int_as_float(e0.y), w1 = __int_as_float(e1.y);
        float w2 = __int_as_float(e2.y), w3 = __int_as_float(e3.y);
        float4 v0 = ldbf4(in + (size_t)e0.x * istride + c4);
        float4 v1 = ldbf4(in + (size_t)e1.x * istride + c4);
        float4 v2 = ldbf4(in + (size_t)e2.x * istride + c4);
        float4 v3 = ldbf4(in + (size_t)e3.x * istride + c4);
        acc.x += w0 * v0.x + w1 * v1.x + w2 * v2.x + w3 * v3.x;
        acc.y += w0 * v0.y + w1 * v1.y + w2 * v2.y + w3 * v3.y;
        acc.z += w0 * v0.z + w1 * v1.z + w2 * v2.z + w3 * v3.z;
        acc.w += w0 * v0.w + w1 * v1.w + w2 * v2.w + w3 * v3.w;
    }
    for (; j < end; ++j) {
        int2 e0 = csr[j];
        float w0 = __int_as_float(e0.y);
        float4 v0 = ldbf4(in + (size_t)e0.x * istride + c4);
        acc.x += w0 * v0.x;
        acc.y += w0 * v0.y;
        acc.z += w0 * v0.z;
        acc.w += w0 * v0.w;
    }
    float4 r;
    if (MODE == 0) {
        r = acc;
    } else if (MODE == 1) {
        float4 t = ldbf4(t0 + (size_t)node * t0s + c4);
        r.x = 2.f * acc.x - t.x;
        r.y = 2.f * acc.y - t.y;
        r.z = 2.f * acc.z - t.z;
        r.w = 2.f * acc.w - t.w;
    } else if (MODE == 3) {
        float4 t = ldbf4(t0 + (size_t)node * t0s + c4);
        r.x = t.x + 2.f * acc.x;
        r.y = t.y + 2.f * acc.y;
        r.z = t.z + 2.f * acc.z;
        r.w = t.w + 2.f * acc.w;
    } else {
        float4 t = ldbf4(t0 + (size_t)node * t0s + c4);
        float4 bb = *reinterpret_cast<const float4*>(bias + c4);
        r.x = fmaxf(t.x + acc.x + bb.x, 0.f);
        r.y = fmaxf(t.y + acc.y + bb.y, 0.f);
        r.z = fmaxf(t.z + acc.z + bb.z, 0.f);
        r.w = fmaxf(t.w + acc.w + bb.w, 0.f);
    }
    stbf4(out + (size_t)node * 64 + c4, r.x, r.y, r.z, r.w);
}

// ====== gemmD: V = H @ [W0-W2 | W1 | W2]  (Fin=64 bf16, out stride 192 bf16)
__global__ __launch_bounds__(256) void k_gemmD(const ushort* __restrict__ H,
                                               const float* __restrict__ W,
                                               ushort* __restrict__ V, int N) {
    __shared__ float As[16][68];
    __shared__ float Bs[16][64];
    int by = blockIdx.y;
    const float* Wk = W + by * (64 * 64);
    const float* W2k = W + 2 * (64 * 64);
    int row0 = blockIdx.x * 64;
    int tid = threadIdx.x;
    int tr = tid >> 4, tc = tid & 15;
    float acc[4][4] = {};
    for (int k0 = 0; k0 < 64; k0 += 16) {
        {
            int r = row0 + (tid >> 2);
            int cc = (tid & 3) * 4;
            float4 v = make_float4(0.f, 0.f, 0.f, 0.f);
            if (r < N) v = ldbf4(H + (size_t)r * 64 + k0 + cc);
            As[cc + 0][tid >> 2] = v.x;
            As[cc + 1][tid >> 2] = v.y;
            As[cc + 2][tid >> 2] = v.z;
            As[cc + 3][tid >> 2] = v.w;
        }
        {
            int rr = tid >> 4;
            int cc = (tid & 15) * 4;
            float4 v = *reinterpret_cast<const float4*>(Wk + (k0 + rr) * 64 + cc);
            if (by == 0) {
                float4 w2 = *reinterpret_cast<const float4*>(W2k + (k0 + rr) * 64 + cc);
                v.x -= w2.x; v.y -= w2.y; v.z -= w2.z; v.w -= w2.w;
            }
            *reinterpret_cast<float4*>(&Bs[rr][cc]) = v;
        }
        __syncthreads();
#pragma unroll
        for (int kk = 0; kk < 16; ++kk) {
            float4 a = *reinterpret_cast<const float4*>(&As[kk][tr * 4]);
            float4 b = *reinterpret_cast<const float4*>(&Bs[kk][tc * 4]);
            acc[0][0] += a.x * b.x; acc[0][1] += a.x * b.y; acc[0][2] += a.x * b.z; acc[0][3] += a.x * b.w;
            acc[1][0] += a.y * b.x; acc[1][1] += a.y * b.y; acc[1][2] += a.y * b.z; acc[1][3] += a.y * b.w;
            acc[2][0] += a.z * b.x; acc[2][1] += a.z * b.y; acc[2][2] += a.z * b.z; acc[2][3] += a.z * b.w;
            acc[3][0] += a.w * b.x; acc[3][1] += a.w * b.y; acc[3][2] += a.w * b.z; acc[3][3] += a.w * b.w;
        }
        __syncthreads();
    }
    int cbase = by * 64;
#pragma unroll
    for (int i = 0; i < 4; ++i) {
        int r = row0 + tr * 4 + i;
        if (r >= N) continue;
        stbf4(V + (size_t)r * 192 + cbase + tc * 4,
              acc[i][0], acc[i][1], acc[i][2], acc[i][3]);
    }
}

// == 3-term GEMM + pool (layer 3): relu(T0@W0+T1@W1+T2@W2+b) -> sums (fp32) ==
__global__ __launch_bounds__(256) void k_gemm3p(const ushort* __restrict__ T0,
                                                const ushort* __restrict__ T1,
                                                const ushort* __restrict__ T2,
                                                const float* __restrict__ W,
                                                const float* __restrict__ bias,
                                                int N, int Fin, int Fout,
                                                const int* __restrict__ batch,
                                                float* __restrict__ sums) {
    __shared__ float As[16][68];
    __shared__ float Bs[16][64];
    int row0 = blockIdx.x * 64;
    int col0 = blockIdx.y * 64;
    int tid = threadIdx.x;
    int tr = tid >> 4, tc = tid & 15;
    float acc[4][4] = {};
    const ushort* Ts[3] = {T0, T1, T2};
    for (int k = 0; k < 3; ++k) {
        const ushort* T = Ts[k];
        const float* Wk = W + k * Fin * Fout;
        for (int k0 = 0; k0 < Fin; k0 += 16) {
            {
                int r = row0 + (tid >> 2);
                int cc = (tid & 3) * 4;
                float4 v = make_float4(0.f, 0.f, 0.f, 0.f);
                if (r < N) v = ldbf4(T + (size_t)r * Fin + k0 + cc);
                As[cc + 0][tid >> 2] = v.x;
                As[cc + 1][tid >> 2] = v.y;
                As[cc + 2][tid >> 2] = v.z;
                As[cc + 3][tid >> 2] = v.w;
            }
            {
                int rr = tid >> 4;
                int cc = (tid & 15) * 4;
                *reinterpret_cast<float4*>(&Bs[rr][cc]) =
                    *reinterpret_cast<const float4*>(Wk + (size_t)(k0 + rr) * Fout + col0 + cc);
            }
            __syncthreads();
#pragma unroll
            for (int kk = 0; kk < 16; ++kk) {
                float4 a = *reinterpret_cast<const float4*>(&As[kk][tr * 4]);
                float4 b = *reinterpret_cast<const float4*>(&Bs[kk][tc * 4]);
                acc[0][0] += a.x * b.x; acc[0][1] += a.x * b.y; acc[0][2] += a.x * b.z; acc[0][3] += a.x * b.w;
                acc[1][0] += a.y * b.x; acc[1][1] += a.y * b.y; acc[1][2] += a.y * b.z; acc[1][3] += a.y * b.w;
                acc[2][0] += a.z * b.x; acc[2][1] += a.z * b.y; acc[2][2] += a.z * b.z; acc[2][3] += a.z * b.w;
                acc[3][0] += a.w * b.x; acc[3][1] += a.w * b.y; acc[3][2] += a.w * b.z; acc[3][3] += a.w * b.w;
            }
            __syncthreads();
        }
    }
    __shared__ float ps[64];
    int b0 = batch[row0];
    int b1v = batch[min(row0 + 63, N - 1)];
    if (b0 == b1v) {
        if (tid < 64) ps[tid] = 0.f;
        __syncthreads();
#pragma unroll
        for (int j = 0; j < 4; ++j) {
            float cs = 0.f;
#pragma unroll
            for (int i = 0; i < 4; ++i) {
                int r = row0 + tr * 4 + i;
                if (r < N) cs += fmaxf(acc[i][j] + bias[col0 + tc * 4 + j], 0.f);
            }
            atomicAdd(&ps[tc * 4 + j], cs);
        }
        __syncthreads();
        if (tid < 64) atomicAdd(&sums[b0 * 128 + col0 + tid], ps[tid]);
    } else {
#pragma unroll
        for (int i = 0; i < 4; ++i) {
            int r = row0 + tr * 4 + i;
            if (r >= N) continue;
#pragma unroll
            for (int j = 0; j < 4; ++j) {
                int cgl = col0 + tc * 4 + j;
                float v = fmaxf(acc[i][j] + bias[cgl], 0.f);
                atomicAdd(&sums[batch[r] * 128 + cgl], v);
            }
        }
    }
}

// ================= head (graph starts computed in-kernel) =================
__global__ __launch_bounds__(640) void k_head(const float* __restrict__ sums,
                                              const int* __restrict__ batch, int N,
                                              const float* __restrict__ linW,
                                              const float* __restrict__ linb,
                                              float* __restrict__ out) {
    __shared__ int st[65];
    int t = threadIdx.x;
    if (t <= 64) {
        if (t == 64) {
            st[64] = N;
        } else {
            int lo = 0, hi = N;
            while (lo < hi) {
                int mid = (lo + hi) >> 1;
                if (batch[mid] < t) lo = mid + 1; else hi = mid;
            }
            st[t] = lo;
        }
    }
    __syncthreads();
    if (t >= NG * 10) return;
    int g = t / 10, o = t % 10;
    float cnt = (float)(st[g + 1] - st[g]);
    float inv = 1.f / fmaxf(cnt, 1.f);
    float acc = 0.f;
#pragma unroll 8
    for (int k = 0; k < 128; ++k) acc += sums[g * 128 + k] * linW[k * 10 + o];
    out[t] = acc * inv + linb[o];
}

// ================= launch =================
extern "C" void kernel_launch(void* const* d_in, const int* in_sizes, int n_in,
                              void* d_out, int out_size, void* d_ws, size_t ws_size,
                              hipStream_t stream) {
    const float* x = (const float*)d_in[0];
    const int* ei = (const int*)d_in[1];
    const float* ew = (const float*)d_in[2];
    const int* batch = (const int*)d_in[3];
    const float* W1 = (const float*)d_in[4];
    const float* b1 = (const float*)d_in[5];
    const float* W2 = (const float*)d_in[6];
    const float* b2 = (const float*)d_in[7];
    const float* W3 = (const float*)d_in[8];
    const float* b3 = (const float*)d_in[9];
    const float* linW = (const float*)d_in[10];
    const float* linb = (const float*)d_in[11];

    const int E = in_sizes[1] / 2;   // 1,600,000
    const int N = in_sizes[0] / 128; // 100,000
    const int* src = ei;
    const int* dst = ei + E;

    float* ws = (float*)d_ws;
    int2*   csr    = (int2*)ws;                        // E entries -> 3,200,512 f
    int*    rank   = (int*)(ws + 3200512);             // 1,600,256
    int*    cursor = rank + 1600256;                   // N+1 -> 100,352 (starts)
    float*  dinv   = (float*)(cursor + 100352);        // 100,352 (deg then dinv)
    int*    bsum   = (int*)(dinv + 100352);            // 256
    int*    boff   = bsum + 256;                       // 256
    ushort* Ub     = (ushort*)(boff + 256);            // N x 192 bf16 (V reuses)
    ushort* R      = Ub + 19200256;                    // N x 64 bf16 (then A3)
    ushort* H1     = R + 6400256;
    ushort* H2     = H1 + 6400256;
    ushort* B3     = H2 + 6400256;
    float*  sums   = (float*)(B3 + 6400256);           // 8,192 fp32

    ushort* A3 = R;

    const int TB = 256;
    auto blocks = [](long long t, int b) { return (int)((t + b - 1) / b); };
    const int PG64 = blocks((long long)N * 16, TB);
    const int NB = (N + 1023) / 1024;       // scan blocks
    const int GX = (N + 63) / 64;           // gemm x-blocks
    const int EB = blocks(E, TB);           // edge blocks

    // ---- memsets up front (cursor[N+1] + deg contiguous; sums) ----
    hipMemsetAsync(cursor, 0, (100352 + 100352) * sizeof(int), stream);
    hipMemsetAsync(sums, 0, NG * 128 * sizeof(float), stream);

    // ---- pre1: gemmU(y0,y1,y2) first, then edges (deg + hist + rank) ----
    k_pre1<<<3 * GX + EB, TB, 0, stream>>>(x, W1, Ub, N, src, dst, ew,
                                           dinv, cursor, rank, E, GX);
    // ---- dinv + scan (cursor -> row starts; cursor[N]=E) ----
    k_scan_a<<<NB, 1024, 0, stream>>>(cursor, bsum, dinv, N);
    k_scan_b<<<1, 128, 0, stream>>>(bsum, boff, NB);
    k_scan_c<<<NB, 1024, 0, stream>>>(cursor, boff, N, E);
    // ---- fill (no atomics) ----
    k_fill<<<EB, TB, 0, stream>>>(src, dst, ew, dinv, cursor, rank, csr, E);

    // ---- layer 1: R = U1 + 2*L(U2); H1 = relu(U0' + L(R) + b1) ----
    k_prop64<3><<<PG64, TB, 0, stream>>>(cursor, csr, Ub + 128, 192, R,
                                         Ub + 64, 192, nullptr, N);
    k_prop64<4><<<PG64, TB, 0, stream>>>(cursor, csr, R, 64, H1,
                                         Ub, 192, b1, N);

    // ---- layer 2: V = H1@[W0-W2|W1|W2]; R = V1 + 2*L(V2); H2 = relu(V0'+L(R)+b2)
    {
        dim3 g(GX, 3);
        k_gemmD<<<g, TB, 0, stream>>>(H1, W2, Ub, N);
    }
    k_prop64<3><<<PG64, TB, 0, stream>>>(cursor, csr, Ub + 128, 192, R,
                                         Ub + 64, 192, nullptr, N);
    k_prop64<4><<<PG64, TB, 0, stream>>>(cursor, csr, R, 64, H2,
                                         Ub, 192, b2, N);

    // ---- layer 3: A3 = L(H2); B3 = 2*L(A3) - H2; gemm3+pool ----
    k_prop64<0><<<PG64, TB, 0, stream>>>(cursor, csr, H2, 64, A3,
                                         nullptr, 0, nullptr, N);
    k_prop64<1><<<PG64, TB, 0, stream>>>(cursor, csr, A3, 64, B3,
                                         H2, 64, nullptr, N);
    {
        dim3 g(GX, 2);
        k_gemm3p<<<g, TB, 0, stream>>>(H2, A3, B3, W3, b3, N, 64, 128, batch, sums);
    }

    // ---- head ----
    k_head<<<1, 640, 0, stream>>>(sums, batch, N, linW, linb, (float*)d_out);
}

// Round 12
// 693.338 us; speedup vs baseline: 1.2724x; 1.0232x over previous
//
#include <hip/hip_runtime.h>

#define NN 100000
#define NG 64

// ---------------- bf16 helpers (storage only; math in fp32) ----------------
__device__ __forceinline__ float bf2f(ushort s) {
    return __uint_as_float(((unsigned int)s) << 16);
}
__device__ __forceinline__ ushort f2bf(float f) {
    unsigned int u = __float_as_uint(f);
    u += 0x7FFFu + ((u >> 16) & 1u);  // round-to-nearest-even
    return (ushort)(u >> 16);
}
__device__ __forceinline__ float4 ldbf4(const ushort* p) {
    ushort4 s = *reinterpret_cast<const ushort4*>(p);
    return make_float4(bf2f(s.x), bf2f(s.y), bf2f(s.z), bf2f(s.w));
}
__device__ __forceinline__ void stbf4(ushort* p, float a, float b, float c, float d) {
    ushort4 s = make_ushort4(f2bf(a), f2bf(b), f2bf(c), f2bf(d));
    *reinterpret_cast<ushort4*>(p) = s;
}
// 16B-wide bf16x8 load/store (int4 granule)
__device__ __forceinline__ void ldbf8(const ushort* p, float* f) {
    int4 v = *reinterpret_cast<const int4*>(p);
    unsigned a = (unsigned)v.x, b = (unsigned)v.y, c = (unsigned)v.z, d = (unsigned)v.w;
    f[0] = __uint_as_float(a << 16); f[1] = __uint_as_float(a & 0xFFFF0000u);
    f[2] = __uint_as_float(b << 16); f[3] = __uint_as_float(b & 0xFFFF0000u);
    f[4] = __uint_as_float(c << 16); f[5] = __uint_as_float(c & 0xFFFF0000u);
    f[6] = __uint_as_float(d << 16); f[7] = __uint_as_float(d & 0xFFFF0000u);
}
__device__ __forceinline__ void stbf8(ushort* p, const float* f) {
    int4 v;
    v.x = (int)(((unsigned)f2bf(f[1]) << 16) | f2bf(f[0]));
    v.y = (int)(((unsigned)f2bf(f[3]) << 16) | f2bf(f[2]));
    v.z = (int)(((unsigned)f2bf(f[5]) << 16) | f2bf(f[4]));
    v.w = (int)(((unsigned)f2bf(f[7]) << 16) | f2bf(f[6]));
    *reinterpret_cast<int4*>(p) = v;
}

// ======================= gemmU body: U[:,by*64:+64] = x @ Wsel ==============
// by==0 uses W[0]-W[2]; out stride 192 (bf16). Fin=128, x fp32.
__device__ __forceinline__ void gemmU_body(const float* __restrict__ x,
                                           const float* __restrict__ W,
                                           ushort* __restrict__ U, int N,
                                           int bx, int by) {
    __shared__ float As[16][68];
    __shared__ float Bs[16][64];
    const float* Wk = W + by * (128 * 64);
    const float* W2k = W + 2 * (128 * 64);
    int row0 = bx * 64;
    int tid = threadIdx.x;
    int tr = tid >> 4, tc = tid & 15;
    float acc[4][4] = {};
    for (int k0 = 0; k0 < 128; k0 += 16) {
        {
            int r = row0 + (tid >> 2);
            int cc = (tid & 3) * 4;
            float4 v = make_float4(0.f, 0.f, 0.f, 0.f);
            if (r < N) v = *reinterpret_cast<const float4*>(x + (size_t)r * 128 + k0 + cc);
            As[cc + 0][tid >> 2] = v.x;
            As[cc + 1][tid >> 2] = v.y;
            As[cc + 2][tid >> 2] = v.z;
            As[cc + 3][tid >> 2] = v.w;
        }
        {
            int rr = tid >> 4;
            int cc = (tid & 15) * 4;
            float4 v = *reinterpret_cast<const float4*>(Wk + (k0 + rr) * 64 + cc);
            if (by == 0) {
                float4 w2 = *reinterpret_cast<const float4*>(W2k + (k0 + rr) * 64 + cc);
                v.x -= w2.x; v.y -= w2.y; v.z -= w2.z; v.w -= w2.w;
            }
            *reinterpret_cast<float4*>(&Bs[rr][cc]) = v;
        }
        __syncthreads();
#pragma unroll
        for (int kk = 0; kk < 16; ++kk) {
            float4 a = *reinterpret_cast<const float4*>(&As[kk][tr * 4]);
            float4 b = *reinterpret_cast<const float4*>(&Bs[kk][tc * 4]);
            acc[0][0] += a.x * b.x; acc[0][1] += a.x * b.y; acc[0][2] += a.x * b.z; acc[0][3] += a.x * b.w;
            acc[1][0] += a.y * b.x; acc[1][1] += a.y * b.y; acc[1][2] += a.y * b.z; acc[1][3] += a.y * b.w;
            acc[2][0] += a.z * b.x; acc[2][1] += a.z * b.y; acc[2][2] += a.z * b.z; acc[2][3] += a.z * b.w;
            acc[3][0] += a.w * b.x; acc[3][1] += a.w * b.y; acc[3][2] += a.w * b.z; acc[3][3] += a.w * b.w;
        }
        __syncthreads();
    }
    int cbase = by * 64;
#pragma unroll
    for (int i = 0; i < 4; ++i) {
        int r = row0 + tr * 4 + i;
        if (r >= N) continue;
        stbf4(U + (size_t)r * 192 + cbase + tc * 4,
              acc[i][0], acc[i][1], acc[i][2], acc[i][3]);
    }
}

// ====== pre1: gemmU(y=0,1,2) blocks FIRST, then edges (deg+hist+rank) =======
__global__ __launch_bounds__(256) void k_pre1(const float* __restrict__ x,
                                              const float* __restrict__ W1,
                                              ushort* __restrict__ U, int N,
                                              const int* __restrict__ src,
                                              const int* __restrict__ dst,
                                              const float* __restrict__ ew,
                                              float* __restrict__ deg,
                                              int* __restrict__ cnt,
                                              int* __restrict__ rank, int E,
                                              int gx) {
    int b = blockIdx.x;
    if (b < 3 * gx) {
        gemmU_body(x, W1, U, N, b % gx, b / gx);
    } else {
        int e = (b - 3 * gx) * 256 + threadIdx.x;
        if (e < E) {
            atomicAdd(&deg[src[e]], ew[e]);
            rank[e] = atomicAdd(&cnt[dst[e]], 1);
        }
    }
}

// ====== fill (no atomics): pos = starts[dst] + rank ========================
__global__ __launch_bounds__(256) void k_fill(const int* __restrict__ src,
                                              const int* __restrict__ dst,
                                              const float* __restrict__ ew,
                                              const float* __restrict__ dinv,
                                              const int* __restrict__ starts,
                                              const int* __restrict__ rank,
                                              int2* __restrict__ csr, int E) {
    int e = blockIdx.x * 256 + threadIdx.x;
    if (e >= E) return;
    int s = src[e], d = dst[e];
    int pos = starts[d] + rank[e];
    float w = -dinv[s] * ew[e] * dinv[d];
    csr[pos] = make_int2(s, __float_as_int(w));
}

// ================= scan pass A (+ fused dinv) =================
__global__ __launch_bounds__(1024) void k_scan_a(int* __restrict__ cnt,
                                                 int* __restrict__ bsum,
                                                 float* __restrict__ deg, int N) {
    __shared__ int sh[1024];
    int t = threadIdx.x;
    int idx = blockIdx.x * 1024 + t;
    int v = (idx < N) ? cnt[idx] : 0;
    if (idx < N) {
        float d = deg[idx];
        deg[idx] = (d > 0.f) ? rsqrtf(fmaxf(d, 1e-30f)) : 0.f;
    }
    sh[t] = v;
    __syncthreads();
#pragma unroll
    for (int off = 1; off < 1024; off <<= 1) {
        int tmp = (t >= off) ? sh[t - off] : 0;
        __syncthreads();
        sh[t] += tmp;
        __syncthreads();
    }
    if (idx < N) cnt[idx] = sh[t] - v;  // exclusive
    if (t == 1023) bsum[blockIdx.x] = sh[1023];
}

__global__ __launch_bounds__(128) void k_scan_b(const int* __restrict__ bsum,
                                                int* __restrict__ boff, int nb) {
    __shared__ int sh[128];
    int t = threadIdx.x;
    int v = (t < nb) ? bsum[t] : 0;
    sh[t] = v;
    __syncthreads();
#pragma unroll
    for (int off = 1; off < 128; off <<= 1) {
        int tmp = (t >= off) ? sh[t - off] : 0;
        __syncthreads();
        sh[t] += tmp;
        __syncthreads();
    }
    if (t < nb) boff[t] = sh[t] - v;
}

__global__ __launch_bounds__(1024) void k_scan_c(int* __restrict__ cnt,
                                                 const int* __restrict__ boff,
                                                 int N, int E) {
    int idx = blockIdx.x * 1024 + threadIdx.x;
    if (idx < N) cnt[idx] += boff[blockIdx.x];
    if (idx == 0) cnt[N] = E;  // sentinel row end
}

// ===== propagation (CSR gather, F=64 bf16 rows, 8 lanes x 16B per node) =====
// MODE 0: out = acc
// MODE 1: out = 2*acc - t0                      (layer-3 T2 step)
// MODE 3: out = t0 + 2*acc                      (R-step, t0 = U1/V1 slice)
// MODE 4: out = relu(t0 + acc + bias)           (H-step, t0 = U0'/V0' slice)
template <int MODE>
__global__ __launch_bounds__(256) void k_prop64(const int* __restrict__ rs,
                                                const int2* __restrict__ csr,
                                                const ushort* __restrict__ in,
                                                int istride,
                                                ushort* __restrict__ out,
                                                const ushort* __restrict__ t0,
                                                int t0s,
                                                const float* __restrict__ bias,
                                                int N) {
    int tid = blockIdx.x * 256 + threadIdx.x;
    int node = tid >> 3;
    int lane = tid & 7;
    if (node >= N) return;
    int start = rs[node];
    int end = rs[node + 1];
    float acc[8] = {};
    int c8 = lane * 8;
    int j = start;
    for (; j + 4 <= end; j += 4) {
        int2 e0 = csr[j + 0], e1 = csr[j + 1], e2 = csr[j + 2], e3 = csr[j + 3];
        float w0 = __int_as_float(e0.y), w1 = __int_as_float(e1.y);
        float w2 = __int_as_float(e2.y), w3 = __int_as_float(e3.y);
        float v0[8], v1[8], v2[8], v3[8];
        ldbf8(in + (size_t)e0.x * istride + c8, v0);
        ldbf8(in + (size_t)e1.x * istride + c8, v1);
        ldbf8(in + (size_t)e2.x * istride + c8, v2);
        ldbf8(in + (size_t)e3.x * istride + c8, v3);
#pragma unroll
        for (int i = 0; i < 8; ++i)
            acc[i] += w0 * v0[i] + w1 * v1[i] + w2 * v2[i] + w3 * v3[i];
    }
    for (; j < end; ++j) {
        int2 e0 = csr[j];
        float w0 = __int_as_float(e0.y);
        float v0[8];
        ldbf8(in + (size_t)e0.x * istride + c8, v0);
#pragma unroll
        for (int i = 0; i < 8; ++i) acc[i] += w0 * v0[i];
    }
    float r[8];
    if (MODE == 0) {
#pragma unroll
        for (int i = 0; i < 8; ++i) r[i] = acc[i];
    } else if (MODE == 1) {
        float t[8];
        ldbf8(t0 + (size_t)node * t0s + c8, t);
#pragma unroll
        for (int i = 0; i < 8; ++i) r[i] = 2.f * acc[i] - t[i];
    } else if (MODE == 3) {
        float t[8];
        ldbf8(t0 + (size_t)node * t0s + c8, t);
#pragma unroll
        for (int i = 0; i < 8; ++i) r[i] = t[i] + 2.f * acc[i];
    } else {
        float t[8];
        ldbf8(t0 + (size_t)node * t0s + c8, t);
        float4 b0 = *reinterpret_cast<const float4*>(bias + c8);
        float4 b1 = *reinterpret_cast<const float4*>(bias + c8 + 4);
        r[0] = fmaxf(t[0] + acc[0] + b0.x, 0.f);
        r[1] = fmaxf(t[1] + acc[1] + b0.y, 0.f);
        r[2] = fmaxf(t[2] + acc[2] + b0.z, 0.f);
        r[3] = fmaxf(t[3] + acc[3] + b0.w, 0.f);
        r[4] = fmaxf(t[4] + acc[4] + b1.x, 0.f);
        r[5] = fmaxf(t[5] + acc[5] + b1.y, 0.f);
        r[6] = fmaxf(t[6] + acc[6] + b1.z, 0.f);
        r[7] = fmaxf(t[7] + acc[7] + b1.w, 0.f);
    }
    stbf8(out + (size_t)node * 64 + c8, r);
}

// ====== gemmD: V = H @ [W0-W2 | W1 | W2]  (Fin=64 bf16, out stride 192 bf16)
__global__ __launch_bounds__(256) void k_gemmD(const ushort* __restrict__ H,
                                               const float* __restrict__ W,
                                               ushort* __restrict__ V, int N) {
    __shared__ float As[16][68];
    __shared__ float Bs[16][64];
    int by = blockIdx.y;
    const float* Wk = W + by * (64 * 64);
    const float* W2k = W + 2 * (64 * 64);
    int row0 = blockIdx.x * 64;
    int tid = threadIdx.x;
    int tr = tid >> 4, tc = tid & 15;
    float acc[4][4] = {};
    for (int k0 = 0; k0 < 64; k0 += 16) {
        {
            int r = row0 + (tid >> 2);
            int cc = (tid & 3) * 4;
            float4 v = make_float4(0.f, 0.f, 0.f, 0.f);
            if (r < N) v = ldbf4(H + (size_t)r * 64 + k0 + cc);
            As[cc + 0][tid >> 2] = v.x;
            As[cc + 1][tid >> 2] = v.y;
            As[cc + 2][tid >> 2] = v.z;
            As[cc + 3][tid >> 2] = v.w;
        }
        {
            int rr = tid >> 4;
            int cc = (tid & 15) * 4;
            float4 v = *reinterpret_cast<const float4*>(Wk + (k0 + rr) * 64 + cc);
            if (by == 0) {
                float4 w2 = *reinterpret_cast<const float4*>(W2k + (k0 + rr) * 64 + cc);
                v.x -= w2.x; v.y -= w2.y; v.z -= w2.z; v.w -= w2.w;
            }
            *reinterpret_cast<float4*>(&Bs[rr][cc]) = v;
        }
        __syncthreads();
#pragma unroll
        for (int kk = 0; kk < 16; ++kk) {
            float4 a = *reinterpret_cast<const float4*>(&As[kk][tr * 4]);
            float4 b = *reinterpret_cast<const float4*>(&Bs[kk][tc * 4]);
            acc[0][0] += a.x * b.x; acc[0][1] += a.x * b.y; acc[0][2] += a.x * b.z; acc[0][3] += a.x * b.w;
            acc[1][0] += a.y * b.x; acc[1][1] += a.y * b.y; acc[1][2] += a.y * b.z; acc[1][3] += a.y * b.w;
            acc[2][0] += a.z * b.x; acc[2][1] += a.z * b.y; acc[2][2] += a.z * b.z; acc[2][3] += a.z * b.w;
            acc[3][0] += a.w * b.x; acc[3][1] += a.w * b.y; acc[3][2] += a.w * b.z; acc[3][3] += a.w * b.w;
        }
        __syncthreads();
    }
    int cbase = by * 64;
#pragma unroll
    for (int i = 0; i < 4; ++i) {
        int r = row0 + tr * 4 + i;
        if (r >= N) continue;
        stbf4(V + (size_t)r * 192 + cbase + tc * 4,
              acc[i][0], acc[i][1], acc[i][2], acc[i][3]);
    }
}

// == 3-term GEMM + pool (layer 3): relu(T0@W0+T1@W1+T2@W2+b) -> sums (fp32) ==
__global__ __launch_bounds__(256) void k_gemm3p(const ushort* __restrict__ T0,
                                                const ushort* __restrict__ T1,
                                                const ushort* __restrict__ T2,
                                                const float* __restrict__ W,
                                                const float* __restrict__ bias,
                                                int N, int Fin, int Fout,
                                                const int* __restrict__ batch,
                                                float* __restrict__ sums) {
    __shared__ float As[16][68];
    __shared__ float Bs[16][64];
    int row0 = blockIdx.x * 64;
    int col0 = blockIdx.y * 64;
    int tid = threadIdx.x;
    int tr = tid >> 4, tc = tid & 15;
    float acc[4][4] = {};
    const ushort* Ts[3] = {T0, T1, T2};
    for (int k = 0; k < 3; ++k) {
        const ushort* T = Ts[k];
        const float* Wk = W + k * Fin * Fout;
        for (int k0 = 0; k0 < Fin; k0 += 16) {
            {
                int r = row0 + (tid >> 2);
                int cc = (tid & 3) * 4;
                float4 v = make_float4(0.f, 0.f, 0.f, 0.f);
                if (r < N) v = ldbf4(T + (size_t)r * Fin + k0 + cc);
                As[cc + 0][tid >> 2] = v.x;
                As[cc + 1][tid >> 2] = v.y;
                As[cc + 2][tid >> 2] = v.z;
                As[cc + 3][tid >> 2] = v.w;
            }
            {
                int rr = tid >> 4;
                int cc = (tid & 15) * 4;
                *reinterpret_cast<float4*>(&Bs[rr][cc]) =
                    *reinterpret_cast<const float4*>(Wk + (size_t)(k0 + rr) * Fout + col0 + cc);
            }
            __syncthreads();
#pragma unroll
            for (int kk = 0; kk < 16; ++kk) {
                float4 a = *reinterpret_cast<const float4*>(&As[kk][tr * 4]);
                float4 b = *reinterpret_cast<const float4*>(&Bs[kk][tc * 4]);
                acc[0][0] += a.x * b.x; acc[0][1] += a.x * b.y; acc[0][2] += a.x * b.z; acc[0][3] += a.x * b.w;
                acc[1][0] += a.y * b.x; acc[1][1] += a.y * b.y; acc[1][2] += a.y * b.z; acc[1][3] += a.y * b.w;
                acc[2][0] += a.z * b.x; acc[2][1] += a.z * b.y; acc[2][2] += a.z * b.z; acc[2][3] += a.z * b.w;
                acc[3][0] += a.w * b.x; acc[3][1] += a.w * b.y; acc[3][2] += a.w * b.z; acc[3][3] += a.w * b.w;
            }
            __syncthreads();
        }
    }
    __shared__ float ps[64];
    int b0 = batch[row0];
    int b1v = batch[min(row0 + 63, N - 1)];
    if (b0 == b1v) {
        if (tid < 64) ps[tid] = 0.f;
        __syncthreads();
#pragma unroll
        for (int j = 0; j < 4; ++j) {
            float cs = 0.f;
#pragma unroll
            for (int i = 0; i < 4; ++i) {
                int r = row0 + tr * 4 + i;
                if (r < N) cs += fmaxf(acc[i][j] + bias[col0 + tc * 4 + j], 0.f);
            }
            atomicAdd(&ps[tc * 4 + j], cs);
        }
        __syncthreads();
        if (tid < 64) atomicAdd(&sums[b0 * 128 + col0 + tid], ps[tid]);
    } else {
#pragma unroll
        for (int i = 0; i < 4; ++i) {
            int r = row0 + tr * 4 + i;
            if (r >= N) continue;
#pragma unroll
            for (int j = 0; j < 4; ++j) {
                int cgl = col0 + tc * 4 + j;
                float v = fmaxf(acc[i][j] + bias[cgl], 0.f);
                atomicAdd(&sums[batch[r] * 128 + cgl], v);
            }
        }
    }
}

// ================= head (graph starts computed in-kernel) =================
__global__ __launch_bounds__(640) void k_head(const float* __restrict__ sums,
                                              const int* __restrict__ batch, int N,
                                              const float* __restrict__ linW,
                                              const float* __restrict__ linb,
                                              float* __restrict__ out) {
    __shared__ int st[65];
    int t = threadIdx.x;
    if (t <= 64) {
        if (t == 64) {
            st[64] = N;
        } else {
            int lo = 0, hi = N;
            while (lo < hi) {
                int mid = (lo + hi) >> 1;
                if (batch[mid] < t) lo = mid + 1; else hi = mid;
            }
            st[t] = lo;
        }
    }
    __syncthreads();
    if (t >= NG * 10) return;
    int g = t / 10, o = t % 10;
    float cnt = (float)(st[g + 1] - st[g]);
    float inv = 1.f / fmaxf(cnt, 1.f);
    float acc = 0.f;
#pragma unroll 8
    for (int k = 0; k < 128; ++k) acc += sums[g * 128 + k] * linW[k * 10 + o];
    out[t] = acc * inv + linb[o];
}

// ================= launch =================
extern "C" void kernel_launch(void* const* d_in, const int* in_sizes, int n_in,
                              void* d_out, int out_size, void* d_ws, size_t ws_size,
                              hipStream_t stream) {
    const float* x = (const float*)d_in[0];
    const int* ei = (const int*)d_in[1];
    const float* ew = (const float*)d_in[2];
    const int* batch = (const int*)d_in[3];
    const float* W1 = (const float*)d_in[4];
    const float* b1 = (const float*)d_in[5];
    const float* W2 = (const float*)d_in[6];
    const float* b2 = (const float*)d_in[7];
    const float* W3 = (const float*)d_in[8];
    const float* b3 = (const float*)d_in[9];
    const float* linW = (const float*)d_in[10];
    const float* linb = (const float*)d_in[11];

    const int E = in_sizes[1] / 2;   // 1,600,000
    const int N = in_sizes[0] / 128; // 100,000
    const int* src = ei;
    const int* dst = ei + E;

    float* ws = (float*)d_ws;
    int2*   csr    = (int2*)ws;                        // E entries -> 3,200,512 f
    int*    rank   = (int*)(ws + 3200512);             // 1,600,256
    int*    cursor = rank + 1600256;                   // N+1 -> 100,352 (starts)
    float*  dinv   = (float*)(cursor + 100352);        // 100,352 (deg then dinv)
    int*    bsum   = (int*)(dinv + 100352);            // 256
    int*    boff   = bsum + 256;                       // 256
    ushort* Ub     = (ushort*)(boff + 256);            // N x 192 bf16 (V reuses)
    ushort* R      = Ub + 19200256;                    // N x 64 bf16 (then A3)
    ushort* H1     = R + 6400256;
    ushort* H2     = H1 + 6400256;
    ushort* B3     = H2 + 6400256;
    float*  sums   = (float*)(B3 + 6400256);           // 8,192 fp32

    ushort* A3 = R;

    const int TB = 256;
    auto blocks = [](long long t, int b) { return (int)((t + b - 1) / b); };
    const int PG64 = blocks((long long)N * 8, TB);
    const int NB = (N + 1023) / 1024;       // scan blocks
    const int GX = (N + 63) / 64;           // gemm x-blocks
    const int EB = blocks(E, TB);           // edge blocks

    // ---- memsets up front (cursor[N+1] + deg contiguous; sums) ----
    hipMemsetAsync(cursor, 0, (100352 + 100352) * sizeof(int), stream);
    hipMemsetAsync(sums, 0, NG * 128 * sizeof(float), stream);

    // ---- pre1: gemmU(y0,y1,y2) first, then edges (deg + hist + rank) ----
    k_pre1<<<3 * GX + EB, TB, 0, stream>>>(x, W1, Ub, N, src, dst, ew,
                                           dinv, cursor, rank, E, GX);
    // ---- dinv + scan (cursor -> row starts; cursor[N]=E) ----
    k_scan_a<<<NB, 1024, 0, stream>>>(cursor, bsum, dinv, N);
    k_scan_b<<<1, 128, 0, stream>>>(bsum, boff, NB);
    k_scan_c<<<NB, 1024, 0, stream>>>(cursor, boff, N, E);
    // ---- fill (no atomics) ----
    k_fill<<<EB, TB, 0, stream>>>(src, dst, ew, dinv, cursor, rank, csr, E);

    // ---- layer 1: R = U1 + 2*L(U2); H1 = relu(U0' + L(R) + b1) ----
    k_prop64<3><<<PG64, TB, 0, stream>>>(cursor, csr, Ub + 128, 192, R,
                                         Ub + 64, 192, nullptr, N);
    k_prop64<4><<<PG64, TB, 0, stream>>>(cursor, csr, R, 64, H1,
                                         Ub, 192, b1, N);

    // ---- layer 2: V = H1@[W0-W2|W1|W2]; R = V1 + 2*L(V2); H2 = relu(V0'+L(R)+b2)
    {
        dim3 g(GX, 3);
        k_gemmD<<<g, TB, 0, stream>>>(H1, W2, Ub, N);
    }
    k_prop64<3><<<PG64, TB, 0, stream>>>(cursor, csr, Ub + 128, 192, R,
                                         Ub + 64, 192, nullptr, N);
    k_prop64<4><<<PG64, TB, 0, stream>>>(cursor, csr, R, 64, H2,
                                         Ub, 192, b2, N);

    // ---- layer 3: A3 = L(H2); B3 = 2*L(A3) - H2; gemm3+pool ----
    k_prop64<0><<<PG64, TB, 0, stream>>>(cursor, csr, H2, 64, A3,
                                         nullptr, 0, nullptr, N);
    k_prop64<1><<<PG64, TB, 0, stream>>>(cursor, csr, A3, 64, B3,
                                         H2, 64, nullptr, N);
    {
        dim3 g(GX, 2);
        k_gemm3p<<<g, TB, 0, stream>>>(H2, A3, B3, W3, b3, N, 64, 128, batch, sums);
    }

    // ---- head ----
    k_head<<<1, 640, 0, stream>>>(sums, batch, N, linW, linb, (float*)d_out);
}

// Round 13
// 655.023 us; speedup vs baseline: 1.3468x; 1.0585x over previous
//
#include <hip/hip_runtime.h>

#define NN 100000
#define NG 64

typedef __attribute__((ext_vector_type(8))) short bf16x8;
typedef __attribute__((ext_vector_type(4))) float f32x4;

// ---------------- bf16 helpers (storage only; math in fp32) ----------------
__device__ __forceinline__ float bf2f(ushort s) {
    return __uint_as_float(((unsigned int)s) << 16);
}
__device__ __forceinline__ ushort f2bf(float f) {
    unsigned int u = __float_as_uint(f);
    u += 0x7FFFu + ((u >> 16) & 1u);  // round-to-nearest-even
    return (ushort)(u >> 16);
}
// 16B-wide bf16x8 load/store (int4 granule)
__device__ __forceinline__ void ldbf8(const ushort* p, float* f) {
    int4 v = *reinterpret_cast<const int4*>(p);
    unsigned a = (unsigned)v.x, b = (unsigned)v.y, c = (unsigned)v.z, d = (unsigned)v.w;
    f[0] = __uint_as_float(a << 16); f[1] = __uint_as_float(a & 0xFFFF0000u);
    f[2] = __uint_as_float(b << 16); f[3] = __uint_as_float(b & 0xFFFF0000u);
    f[4] = __uint_as_float(c << 16); f[5] = __uint_as_float(c & 0xFFFF0000u);
    f[6] = __uint_as_float(d << 16); f[7] = __uint_as_float(d & 0xFFFF0000u);
}
__device__ __forceinline__ void stbf8(ushort* p, const float* f) {
    int4 v;
    v.x = (int)(((unsigned)f2bf(f[1]) << 16) | f2bf(f[0]));
    v.y = (int)(((unsigned)f2bf(f[3]) << 16) | f2bf(f[2]));
    v.z = (int)(((unsigned)f2bf(f[5]) << 16) | f2bf(f[4]));
    v.w = (int)(((unsigned)f2bf(f[7]) << 16) | f2bf(f[6]));
    *reinterpret_cast<int4*>(p) = v;
}

// ================= MFMA tile machinery (64x64 tile, 4 waves) ================
// As[row][k] 64x32 (+8 pad); Bs[col][k] 64x32 (+8 pad). K-step = 32.
// Fragment: lane reads 16B at [ (lane&15) + base ][ (lane>>4)*8 ].
// C/D (m89-verified): col = lane&15, row = (lane>>4)*4 + reg.

__device__ __forceinline__ void stageA_f32(ushort (*As)[40], const float* __restrict__ src,
                                           int stride, int row0, int k0, int N, int tid) {
    int row = tid >> 2, koff = (tid & 3) * 8;
    int r = row0 + row;
    float f[8] = {};
    if (r < N) {
        const float* p = src + (size_t)r * stride + k0 + koff;
        float4 a = *reinterpret_cast<const float4*>(p);
        float4 b = *reinterpret_cast<const float4*>(p + 4);
        f[0] = a.x; f[1] = a.y; f[2] = a.z; f[3] = a.w;
        f[4] = b.x; f[5] = b.y; f[6] = b.z; f[7] = b.w;
    }
    stbf8(&As[row][koff], f);
}

__device__ __forceinline__ void stageA_bf16(ushort (*As)[40], const ushort* __restrict__ src,
                                            int stride, int row0, int k0, int N, int tid) {
    int row = tid >> 2, koff = (tid & 3) * 8;
    int r = row0 + row;
    int4 v = make_int4(0, 0, 0, 0);
    if (r < N) v = *reinterpret_cast<const int4*>(src + (size_t)r * stride + k0 + koff);
    *reinterpret_cast<int4*>(&As[row][koff]) = v;
}

// W fp32 row-major [K][Nout] -> Bs[col][k] bf16 (transposed); optional W2 subtract
__device__ __forceinline__ void stageB(ushort (*Bs)[40], const float* __restrict__ Wk,
                                       const float* __restrict__ W2k,
                                       int Nout, int col0, int k0, int tid) {
    int kk = tid >> 3;
    int cg = (tid & 7) * 8;
    const float* p = Wk + (size_t)(k0 + kk) * Nout + col0 + cg;
    float4 a = *reinterpret_cast<const float4*>(p);
    float4 b = *reinterpret_cast<const float4*>(p + 4);
    if (W2k) {
        const float* q = W2k + (size_t)(k0 + kk) * Nout + col0 + cg;
        float4 c = *reinterpret_cast<const float4*>(q);
        float4 d = *reinterpret_cast<const float4*>(q + 4);
        a.x -= c.x; a.y -= c.y; a.z -= c.z; a.w -= c.w;
        b.x -= d.x; b.y -= d.y; b.z -= d.z; b.w -= d.w;
    }
    Bs[cg + 0][kk] = f2bf(a.x); Bs[cg + 1][kk] = f2bf(a.y);
    Bs[cg + 2][kk] = f2bf(a.z); Bs[cg + 3][kk] = f2bf(a.w);
    Bs[cg + 4][kk] = f2bf(b.x); Bs[cg + 5][kk] = f2bf(b.y);
    Bs[cg + 6][kk] = f2bf(b.z); Bs[cg + 7][kk] = f2bf(b.w);
}

__device__ __forceinline__ void mfma_step(const ushort (*As)[40], const ushort (*Bs)[40],
                                          int wave, int lane, f32x4* acc) {
    int idx = lane & 15, kg = lane >> 4;
    bf16x8 af = *reinterpret_cast<const bf16x8*>(&As[wave * 16 + idx][kg * 8]);
#pragma unroll
    for (int t = 0; t < 4; ++t) {
        bf16x8 bf = *reinterpret_cast<const bf16x8*>(&Bs[t * 16 + idx][kg * 8]);
        acc[t] = __builtin_amdgcn_mfma_f32_16x16x32_bf16(af, bf, acc[t], 0, 0, 0);
    }
}

// ======================= gemmU body: U[:,by*64:+64] = x @ Wsel ==============
// by==0 uses W[0]-W[2]; out stride 192 (bf16). Fin=128, x fp32. MFMA.
__device__ __forceinline__ void gemmU_body(const float* __restrict__ x,
                                           const float* __restrict__ W,
                                           ushort* __restrict__ U, int N,
                                           int bx, int by) {
    __shared__ ushort As[64][40];
    __shared__ ushort Bs[64][40];
    const float* Wk = W + by * (128 * 64);
    const float* W2k = (by == 0) ? (W + 2 * (128 * 64)) : nullptr;
    int row0 = bx * 64;
    int tid = threadIdx.x;
    int wave = tid >> 6, lane = tid & 63;
    f32x4 acc[4] = {{0.f,0.f,0.f,0.f},{0.f,0.f,0.f,0.f},{0.f,0.f,0.f,0.f},{0.f,0.f,0.f,0.f}};
    for (int k0 = 0; k0 < 128; k0 += 32) {
        stageA_f32(As, x, 128, row0, k0, N, tid);
        stageB(Bs, Wk, W2k, 64, 0, k0, tid);
        __syncthreads();
        mfma_step(As, Bs, wave, lane, acc);
        __syncthreads();
    }
    int cbase = by * 64;
    int rbase = row0 + wave * 16 + ((lane >> 4) << 2);
    int col = lane & 15;
#pragma unroll
    for (int i = 0; i < 4; ++i) {
        int r = rbase + i;
        if (r >= N) continue;
#pragma unroll
        for (int t = 0; t < 4; ++t)
            U[(size_t)r * 192 + cbase + t * 16 + col] = f2bf(acc[t][i]);
    }
}

// ====== pre1: gemmU(y=0,1,2) blocks FIRST, then edges (deg+hist+rank) =======
__global__ __launch_bounds__(256) void k_pre1(const float* __restrict__ x,
                                              const float* __restrict__ W1,
                                              ushort* __restrict__ U, int N,
                                              const int* __restrict__ src,
                                              const int* __restrict__ dst,
                                              const float* __restrict__ ew,
                                              float* __restrict__ deg,
                                              int* __restrict__ cnt,
                                              int* __restrict__ rank, int E,
                                              int gx) {
    int b = blockIdx.x;
    if (b < 3 * gx) {
        gemmU_body(x, W1, U, N, b % gx, b / gx);
    } else {
        int e = (b - 3 * gx) * 256 + threadIdx.x;
        if (e < E) {
            atomicAdd(&deg[src[e]], ew[e]);
            rank[e] = atomicAdd(&cnt[dst[e]], 1);
        }
    }
}

// ====== fill (no atomics): pos = starts[dst] + rank ========================
__global__ __launch_bounds__(256) void k_fill(const int* __restrict__ src,
                                              const int* __restrict__ dst,
                                              const float* __restrict__ ew,
                                              const float* __restrict__ dinv,
                                              const int* __restrict__ starts,
                                              const int* __restrict__ rank,
                                              int2* __restrict__ csr, int E) {
    int e = blockIdx.x * 256 + threadIdx.x;
    if (e >= E) return;
    int s = src[e], d = dst[e];
    int pos = starts[d] + rank[e];
    float w = -dinv[s] * ew[e] * dinv[d];
    csr[pos] = make_int2(s, __float_as_int(w));
}

// ================= scan pass A (+ fused dinv) =================
__global__ __launch_bounds__(1024) void k_scan_a(int* __restrict__ cnt,
                                                 int* __restrict__ bsum,
                                                 float* __restrict__ deg, int N) {
    __shared__ int sh[1024];
    int t = threadIdx.x;
    int idx = blockIdx.x * 1024 + t;
    int v = (idx < N) ? cnt[idx] : 0;
    if (idx < N) {
        float d = deg[idx];
        deg[idx] = (d > 0.f) ? rsqrtf(fmaxf(d, 1e-30f)) : 0.f;
    }
    sh[t] = v;
    __syncthreads();
#pragma unroll
    for (int off = 1; off < 1024; off <<= 1) {
        int tmp = (t >= off) ? sh[t - off] : 0;
        __syncthreads();
        sh[t] += tmp;
        __syncthreads();
    }
    if (idx < N) cnt[idx] = sh[t] - v;  // exclusive
    if (t == 1023) bsum[blockIdx.x] = sh[1023];
}

__global__ __launch_bounds__(128) void k_scan_b(const int* __restrict__ bsum,
                                                int* __restrict__ boff, int nb) {
    __shared__ int sh[128];
    int t = threadIdx.x;
    int v = (t < nb) ? bsum[t] : 0;
    sh[t] = v;
    __syncthreads();
#pragma unroll
    for (int off = 1; off < 128; off <<= 1) {
        int tmp = (t >= off) ? sh[t - off] : 0;
        __syncthreads();
        sh[t] += tmp;
        __syncthreads();
    }
    if (t < nb) boff[t] = sh[t] - v;
}

__global__ __launch_bounds__(1024) void k_scan_c(int* __restrict__ cnt,
                                                 const int* __restrict__ boff,
                                                 int N, int E) {
    int idx = blockIdx.x * 1024 + threadIdx.x;
    if (idx < N) cnt[idx] += boff[blockIdx.x];
    if (idx == 0) cnt[N] = E;  // sentinel row end
}

// ===== propagation (CSR gather, F=64 bf16 rows, 8 lanes x 16B per node) =====
// MODE 0: out = acc
// MODE 1: out = 2*acc - t0                      (layer-3 T2 step)
// MODE 3: out = t0 + 2*acc                      (R-step, t0 = U1/V1 slice)
// MODE 4: out = relu(t0 + acc + bias)           (H-step, t0 = U0'/V0' slice)
template <int MODE>
__global__ __launch_bounds__(256) void k_prop64(const int* __restrict__ rs,
                                                const int2* __restrict__ csr,
                                                const ushort* __restrict__ in,
                                                int istride,
                                                ushort* __restrict__ out,
                                                const ushort* __restrict__ t0,
                                                int t0s,
                                                const float* __restrict__ bias,
                                                int N) {
    int tid = blockIdx.x * 256 + threadIdx.x;
    int node = tid >> 3;
    int lane = tid & 7;
    if (node >= N) return;
    int start = rs[node];
    int end = rs[node + 1];
    float acc[8] = {};
    int c8 = lane * 8;
    int j = start;
    for (; j + 4 <= end; j += 4) {
        int2 e0 = csr[j + 0], e1 = csr[j + 1], e2 = csr[j + 2], e3 = csr[j + 3];
        float w0 = __int_as_float(e0.y), w1 = __int_as_float(e1.y);
        float w2 = __int_as_float(e2.y), w3 = __int_as_float(e3.y);
        float v0[8], v1[8], v2[8], v3[8];
        ldbf8(in + (size_t)e0.x * istride + c8, v0);
        ldbf8(in + (size_t)e1.x * istride + c8, v1);
        ldbf8(in + (size_t)e2.x * istride + c8, v2);
        ldbf8(in + (size_t)e3.x * istride + c8, v3);
#pragma unroll
        for (int i = 0; i < 8; ++i)
            acc[i] += w0 * v0[i] + w1 * v1[i] + w2 * v2[i] + w3 * v3[i];
    }
    for (; j < end; ++j) {
        int2 e0 = csr[j];
        float w0 = __int_as_float(e0.y);
        float v0[8];
        ldbf8(in + (size_t)e0.x * istride + c8, v0);
#pragma unroll
        for (int i = 0; i < 8; ++i) acc[i] += w0 * v0[i];
    }
    float r[8];
    if (MODE == 0) {
#pragma unroll
        for (int i = 0; i < 8; ++i) r[i] = acc[i];
    } else if (MODE == 1) {
        float t[8];
        ldbf8(t0 + (size_t)node * t0s + c8, t);
#pragma unroll
        for (int i = 0; i < 8; ++i) r[i] = 2.f * acc[i] - t[i];
    } else if (MODE == 3) {
        float t[8];
        ldbf8(t0 + (size_t)node * t0s + c8, t);
#pragma unroll
        for (int i = 0; i < 8; ++i) r[i] = t[i] + 2.f * acc[i];
    } else {
        float t[8];
        ldbf8(t0 + (size_t)node * t0s + c8, t);
        float4 b0 = *reinterpret_cast<const float4*>(bias + c8);
        float4 b1 = *reinterpret_cast<const float4*>(bias + c8 + 4);
        r[0] = fmaxf(t[0] + acc[0] + b0.x, 0.f);
        r[1] = fmaxf(t[1] + acc[1] + b0.y, 0.f);
        r[2] = fmaxf(t[2] + acc[2] + b0.z, 0.f);
        r[3] = fmaxf(t[3] + acc[3] + b0.w, 0.f);
        r[4] = fmaxf(t[4] + acc[4] + b1.x, 0.f);
        r[5] = fmaxf(t[5] + acc[5] + b1.y, 0.f);
        r[6] = fmaxf(t[6] + acc[6] + b1.z, 0.f);
        r[7] = fmaxf(t[7] + acc[7] + b1.w, 0.f);
    }
    stbf8(out + (size_t)node * 64 + c8, r);
}

// ====== gemmD: V = H @ [W0-W2 | W1 | W2]  (Fin=64 bf16, out stride 192, MFMA)
__global__ __launch_bounds__(256) void k_gemmD(const ushort* __restrict__ H,
                                               const float* __restrict__ W,
                                               ushort* __restrict__ V, int N) {
    __shared__ ushort As[64][40];
    __shared__ ushort Bs[64][40];
    int by = blockIdx.y;
    const float* Wk = W + by * (64 * 64);
    const float* W2k = (by == 0) ? (W + 2 * (64 * 64)) : nullptr;
    int row0 = blockIdx.x * 64;
    int tid = threadIdx.x;
    int wave = tid >> 6, lane = tid & 63;
    f32x4 acc[4] = {{0.f,0.f,0.f,0.f},{0.f,0.f,0.f,0.f},{0.f,0.f,0.f,0.f},{0.f,0.f,0.f,0.f}};
    for (int k0 = 0; k0 < 64; k0 += 32) {
        stageA_bf16(As, H, 64, row0, k0, N, tid);
        stageB(Bs, Wk, W2k, 64, 0, k0, tid);
        __syncthreads();
        mfma_step(As, Bs, wave, lane, acc);
        __syncthreads();
    }
    int cbase = by * 64;
    int rbase = row0 + wave * 16 + ((lane >> 4) << 2);
    int col = lane & 15;
#pragma unroll
    for (int i = 0; i < 4; ++i) {
        int r = rbase + i;
        if (r >= N) continue;
#pragma unroll
        for (int t = 0; t < 4; ++t)
            V[(size_t)r * 192 + cbase + t * 16 + col] = f2bf(acc[t][i]);
    }
}

// == 3-term GEMM + pool (layer 3): relu(T0@W0+T1@W1+T2@W2+b) -> sums (MFMA) ==
__global__ __launch_bounds__(256) void k_gemm3p(const ushort* __restrict__ T0,
                                                const ushort* __restrict__ T1,
                                                const ushort* __restrict__ T2,
                                                const float* __restrict__ W,
                                                const float* __restrict__ bias,
                                                int N,
                                                const int* __restrict__ batch,
                                                float* __restrict__ sums) {
    __shared__ ushort As[64][40];
    __shared__ ushort Bs[64][40];
    __shared__ float ps[64];
    const int Fin = 64, Fout = 128;
    int row0 = blockIdx.x * 64;
    int col0 = blockIdx.y * 64;
    int tid = threadIdx.x;
    int wave = tid >> 6, lane = tid & 63;
    f32x4 acc[4] = {{0.f,0.f,0.f,0.f},{0.f,0.f,0.f,0.f},{0.f,0.f,0.f,0.f},{0.f,0.f,0.f,0.f}};
    const ushort* Ts[3] = {T0, T1, T2};
    for (int k = 0; k < 3; ++k) {
        const float* Wk = W + k * Fin * Fout;
        for (int k0 = 0; k0 < Fin; k0 += 32) {
            stageA_bf16(As, Ts[k], 64, row0, k0, N, tid);
            stageB(Bs, Wk, nullptr, Fout, col0, k0, tid);
            __syncthreads();
            mfma_step(As, Bs, wave, lane, acc);
            __syncthreads();
        }
    }
    int rbase = row0 + wave * 16 + ((lane >> 4) << 2);
    int col = lane & 15;
    int b0 = batch[row0];
    int b1v = batch[min(row0 + 63, N - 1)];
    if (b0 == b1v) {
        if (tid < 64) ps[tid] = 0.f;
        __syncthreads();
#pragma unroll
        for (int i = 0; i < 4; ++i) {
            int r = rbase + i;
            if (r >= N) continue;
#pragma unroll
            for (int t = 0; t < 4; ++t) {
                float v = fmaxf(acc[t][i] + bias[col0 + t * 16 + col], 0.f);
                atomicAdd(&ps[t * 16 + col], v);
            }
        }
        __syncthreads();
        if (tid < 64) atomicAdd(&sums[b0 * 128 + col0 + tid], ps[tid]);
    } else {
#pragma unroll
        for (int i = 0; i < 4; ++i) {
            int r = rbase + i;
            if (r >= N) continue;
#pragma unroll
            for (int t = 0; t < 4; ++t) {
                int cgl = col0 + t * 16 + col;
                float v = fmaxf(acc[t][i] + bias[cgl], 0.f);
                atomicAdd(&sums[batch[r] * 128 + cgl], v);
            }
        }
    }
}

// ================= head (graph starts computed in-kernel) =================
__global__ __launch_bounds__(640) void k_head(const float* __restrict__ sums,
                                              const int* __restrict__ batch, int N,
                                              const float* __restrict__ linW,
                                              const float* __restrict__ linb,
                                              float* __restrict__ out) {
    __shared__ int st[65];
    int t = threadIdx.x;
    if (t <= 64) {
        if (t == 64) {
            st[64] = N;
        } else {
            int lo = 0, hi = N;
            while (lo < hi) {
                int mid = (lo + hi) >> 1;
                if (batch[mid] < t) lo = mid + 1; else hi = mid;
            }
            st[t] = lo;
        }
    }
    __syncthreads();
    if (t >= NG * 10) return;
    int g = t / 10, o = t % 10;
    float cnt = (float)(st[g + 1] - st[g]);
    float inv = 1.f / fmaxf(cnt, 1.f);
    float acc = 0.f;
#pragma unroll 8
    for (int k = 0; k < 128; ++k) acc += sums[g * 128 + k] * linW[k * 10 + o];
    out[t] = acc * inv + linb[o];
}

// ================= launch =================
extern "C" void kernel_launch(void* const* d_in, const int* in_sizes, int n_in,
                              void* d_out, int out_size, void* d_ws, size_t ws_size,
                              hipStream_t stream) {
    const float* x = (const float*)d_in[0];
    const int* ei = (const int*)d_in[1];
    const float* ew = (const float*)d_in[2];
    const int* batch = (const int*)d_in[3];
    const float* W1 = (const float*)d_in[4];
    const float* b1 = (const float*)d_in[5];
    const float* W2 = (const float*)d_in[6];
    const float* b2 = (const float*)d_in[7];
    const float* W3 = (const float*)d_in[8];
    const float* b3 = (const float*)d_in[9];
    const float* linW = (const float*)d_in[10];
    const float* linb = (const float*)d_in[11];

    const int E = in_sizes[1] / 2;   // 1,600,000
    const int N = in_sizes[0] / 128; // 100,000
    const int* src = ei;
    const int* dst = ei + E;

    float* ws = (float*)d_ws;
    int2*   csr    = (int2*)ws;                        // E entries -> 3,200,512 f
    int*    rank   = (int*)(ws + 3200512);             // 1,600,256
    int*    cursor = rank + 1600256;                   // N+1 -> 100,352 (starts)
    float*  dinv   = (float*)(cursor + 100352);        // 100,352 (deg then dinv)
    int*    bsum   = (int*)(dinv + 100352);            // 256
    int*    boff   = bsum + 256;                       // 256
    ushort* Ub     = (ushort*)(boff + 256);            // N x 192 bf16 (V reuses)
    ushort* R      = Ub + 19200256;                    // N x 64 bf16 (then A3)
    ushort* H1     = R + 6400256;
    ushort* H2     = H1 + 6400256;
    ushort* B3     = H2 + 6400256;
    float*  sums   = (float*)(B3 + 6400256);           // 8,192 fp32

    ushort* A3 = R;

    const int TB = 256;
    auto blocks = [](long long t, int b) { return (int)((t + b - 1) / b); };
    const int PG64 = blocks((long long)N * 8, TB);
    const int NB = (N + 1023) / 1024;       // scan blocks
    const int GX = (N + 63) / 64;           // gemm x-blocks
    const int EB = blocks(E, TB);           // edge blocks

    // ---- memsets up front (cursor[N+1] + deg contiguous; sums) ----
    hipMemsetAsync(cursor, 0, (100352 + 100352) * sizeof(int), stream);
    hipMemsetAsync(sums, 0, NG * 128 * sizeof(float), stream);

    // ---- pre1: gemmU(y0,y1,y2) first, then edges (deg + hist + rank) ----
    k_pre1<<<3 * GX + EB, TB, 0, stream>>>(x, W1, Ub, N, src, dst, ew,
                                           dinv, cursor, rank, E, GX);
    // ---- dinv + scan (cursor -> row starts; cursor[N]=E) ----
    k_scan_a<<<NB, 1024, 0, stream>>>(cursor, bsum, dinv, N);
    k_scan_b<<<1, 128, 0, stream>>>(bsum, boff, NB);
    k_scan_c<<<NB, 1024, 0, stream>>>(cursor, boff, N, E);
    // ---- fill (no atomics) ----
    k_fill<<<EB, TB, 0, stream>>>(src, dst, ew, dinv, cursor, rank, csr, E);

    // ---- layer 1: R = U1 + 2*L(U2); H1 = relu(U0' + L(R) + b1) ----
    k_prop64<3><<<PG64, TB, 0, stream>>>(cursor, csr, Ub + 128, 192, R,
                                         Ub + 64, 192, nullptr, N);
    k_prop64<4><<<PG64, TB, 0, stream>>>(cursor, csr, R, 64, H1,
                                         Ub, 192, b1, N);

    // ---- layer 2: V = H1@[W0-W2|W1|W2]; R = V1 + 2*L(V2); H2 = relu(V0'+L(R)+b2)
    {
        dim3 g(GX, 3);
        k_gemmD<<<g, TB, 0, stream>>>(H1, W2, Ub, N);
    }
    k_prop64<3><<<PG64, TB, 0, stream>>>(cursor, csr, Ub + 128, 192, R,
                                         Ub + 64, 192, nullptr, N);
    k_prop64<4><<<PG64, TB, 0, stream>>>(cursor, csr, R, 64, H2,
                                         Ub, 192, b2, N);

    // ---- layer 3: A3 = L(H2); B3 = 2*L(A3) - H2; gemm3+pool ----
    k_prop64<0><<<PG64, TB, 0, stream>>>(cursor, csr, H2, 64, A3,
                                         nullptr, 0, nullptr, N);
    k_prop64<1><<<PG64, TB, 0, stream>>>(cursor, csr, A3, 64, B3,
                                         H2, 64, nullptr, N);
    {
        dim3 g(GX, 2);
        k_gemm3p<<<g, TB, 0, stream>>>(H2, A3, B3, W3, b3, N, batch, sums);
    }

    // ---- head ----
    k_head<<<1, 640, 0, stream>>>(sums, batch, N, linW, linb, (float*)d_out);
}